// Round 14
// baseline (346.419 us; speedup 1.0000x reference)
//
#include <hip/hip_runtime.h>
#include <math.h>

typedef _Float16 f16;
typedef __attribute__((ext_vector_type(4))) _Float16 f16x4;
typedef __attribute__((ext_vector_type(8))) _Float16 f16x8;
typedef __attribute__((ext_vector_type(2))) __fp16 h16x2;
typedef __attribute__((ext_vector_type(4))) __fp16 h16x4;
typedef __attribute__((ext_vector_type(4))) float f32x4;
typedef __attribute__((ext_vector_type(16))) float f32x16;

__device__ __forceinline__ void load_lds16(const void* g, void* l) {
    __builtin_amdgcn_global_load_lds((const __attribute__((address_space(1))) void*)g,
                                     (__attribute__((address_space(3))) void*)l, 16, 0, 0);
}

__device__ __forceinline__ float fast_exp2(float x) {
#if __has_builtin(__builtin_amdgcn_exp2f)
    return __builtin_amdgcn_exp2f(x);
#else
    return __exp2f(x);
#endif
}

#define MFMA32(a, b, c) __builtin_amdgcn_mfma_f32_16x16x32_f16(a, b, c, 0, 0, 0)
#define MFMA3216(a, b, c) __builtin_amdgcn_mfma_f32_32x32x16_f16(a, b, c, 0, 0, 0)

// Device-scope grid barrier: 512 co-resident blocks (guaranteed by
// launch_bounds(256,2) + 32KB LDS -> >=2 blocks/CU x 256 CU). Release
// fence -> device atomicAdd -> AGENT atomic-load spin -> acquire fence.
__device__ __forceinline__ void gridbar(unsigned* c) {
    __syncthreads();
    if (threadIdx.x == 0) {
        __threadfence();
        atomicAdd(c, 1u);
        while (__hip_atomic_load(c, __ATOMIC_RELAXED, __HIP_MEMORY_SCOPE_AGENT) < 512u)
            __builtin_amdgcn_s_sleep(2);
    }
    __syncthreads();
    __threadfence();   // acquire on every thread before next stage's loads
}

// ---------------------------------------------------------------------------
// Helper: softmax HALF a 32-wide S tile (8 f32) -> 1 PV A-fragment.
// ---------------------------------------------------------------------------
__device__ __forceinline__ f16x8 soft_half(const f32x16 sv, const int base,
                                           float2& ls, const h16x2 one2) {
    h16x2 c0 = __builtin_amdgcn_cvt_pkrtz(fast_exp2(sv[base + 0]),
                                          fast_exp2(sv[base + 1]));
    h16x2 c1 = __builtin_amdgcn_cvt_pkrtz(fast_exp2(sv[base + 2]),
                                          fast_exp2(sv[base + 3]));
    h16x2 c2 = __builtin_amdgcn_cvt_pkrtz(fast_exp2(sv[base + 4]),
                                          fast_exp2(sv[base + 5]));
    h16x2 c3 = __builtin_amdgcn_cvt_pkrtz(fast_exp2(sv[base + 6]),
                                          fast_exp2(sv[base + 7]));
    ls.x = __builtin_amdgcn_fdot2(c0, one2, ls.x, false);
    ls.y = __builtin_amdgcn_fdot2(c1, one2, ls.y, false);
    ls.x = __builtin_amdgcn_fdot2(c2, one2, ls.x, false);
    ls.y = __builtin_amdgcn_fdot2(c3, one2, ls.y, false);
    h16x4 plo = __builtin_shufflevector(c0, c1, 0, 1, 2, 3);
    h16x4 phi = __builtin_shufflevector(c2, c3, 0, 1, 2, 3);
    return __builtin_bit_cast(
        f16x8, __builtin_shufflevector(plo, phi, 0, 1, 2, 3, 4, 5, 6, 7));
}

// ---------------------------------------------------------------------------
// Fused kernel: all 4 stages, grid 512, 3 grid barriers. Stage bodies are
// verbatim R12/R13/R8-passing code with block coords derived from bid.
// ---------------------------------------------------------------------------
__global__ __launch_bounds__(256, 2) void fused(
        const float* __restrict__ x, const float* __restrict__ wqkv,
        const float* __restrict__ wout, const float* __restrict__ bias,
        float* __restrict__ out, f16* __restrict__ xh, f16* __restrict__ wqh,
        f16* __restrict__ woh, f16* __restrict__ qb, f16* __restrict__ kb,
        f16* __restrict__ vb, f16* __restrict__ Op, float* __restrict__ Lp,
        unsigned* __restrict__ bar) {
    __shared__ __align__(16) char smem[32768];
    const int tid = threadIdx.x;
    const int bid = blockIdx.x;
    const int w = tid >> 6, lane = tid & 63, l16 = lane & 15, g = lane >> 4;
    const int wm = w >> 1, wn = w & 1;
    const int swz = lane & 7;

    // ===== stage 0: x transpose (blocks 0..255) + weight cvt (256..319) =====
    if (bid < 256) {
        f16 (*t)[65] = (f16(*)[65])smem;      // 8320 B
        const int p0 = (bid & 63) * 64;
        const int c0 = (bid >> 6) * 64;
        const int lp = lane, lq = w;
        for (int i = 0; i < 64; i += 4)
            t[i + lq][lp] = (f16)x[(size_t)(c0 + i + lq) * 4096 + p0 + lp];
        __syncthreads();
        for (int i = 0; i < 64; i += 4)
            xh[(size_t)(p0 + i + lq) * 256 + c0 + lp] = t[lp][i + lq];
    } else if (bid < 320) {
        const int t0 = (bid - 256) * 256 + tid;       // 16384 threads
        for (int i = t0; i < 98304; i += 16384) {     // wqkv: 393216 f32
            float4 u = ((const float4*)wqkv)[i];
            f16x4 hv; hv[0] = (f16)u.x; hv[1] = (f16)u.y;
            hv[2] = (f16)u.z; hv[3] = (f16)u.w;
            ((f16x4*)wqh)[i] = hv;
        }
        for (int i = t0; i < 32768; i += 16384) {     // wout: 131072 f32
            float4 u = ((const float4*)wout)[i];
            f16x4 hv; hv[0] = (f16)u.x; hv[1] = (f16)u.y;
            hv[2] = (f16)u.z; hv[3] = (f16)u.w;
            ((f16x4*)woh)[i] = hv;
        }
    }
    gridbar(bar + 0);

    // ===== stage 1: QKV GEMM (blocks 0..383), R12 single-buffer verbatim ====
    if (bid < 384) {
        f16* As = (f16*)smem;
        f16* Bs = (f16*)(smem + 16384);
        const int K = 256;
        const int mBase = (bid >> 5) * 128, nBase = (bid & 31) * 128;

        f32x4 acc[4][4] = {};

        for (int k0 = 0; k0 < K; k0 += 64) {
            for (int c = 0; c < 4; c++) {
                const int L = c * 256 + w * 64 + lane;
                const int row = L >> 3;
                load_lds16(wqh + (size_t)(mBase + row) * K + k0 +
                               (((L & 7) ^ (row & 7)) * 8),
                           &As[(c * 256 + w * 64) * 8]);
            }
            for (int c = 0; c < 4; c++) {
                const int L = c * 256 + w * 64 + lane;
                const int row = L >> 3;
                load_lds16(xh + (size_t)(nBase + row) * K + k0 +
                               (((L & 7) ^ (row & 7)) * 8),
                           &Bs[(c * 256 + w * 64) * 8]);
            }
            __syncthreads();
            for (int ks = 0; ks < 2; ks++) {
                const int ch = ((ks * 4 + g) ^ swz) * 8;
                f16x8 af[4], bf[4];
                for (int t = 0; t < 4; t++)
                    af[t] = *(const f16x8*)&As[(wm * 64 + t * 16 + l16) * 64 + ch];
                for (int t = 0; t < 4; t++)
                    bf[t] = *(const f16x8*)&Bs[(wn * 64 + t * 16 + l16) * 64 + ch];
                for (int mt = 0; mt < 4; mt++)
                    for (int nt = 0; nt < 4; nt++)
                        acc[mt][nt] = MFMA32(af[mt], bf[nt], acc[mt][nt]);
            }
            __syncthreads();
        }

        const int which = mBase >> 9;  // 0=q, 1=k, 2=v (block-uniform)
        if (which == 2) {
            for (int mt = 0; mt < 4; mt++)
                for (int nt = 0; nt < 4; nt++)
                    for (int r = 0; r < 4; r++) {
                        const int o = mBase + wm * 64 + mt * 16 + g * 4 + r;
                        const int p = nBase + wn * 64 + nt * 16 + l16;
                        const int vd = o - 1024;
                        vb[(size_t)(vd >> 6) * 262144 + (size_t)(p >> 3) * 512 +
                           (size_t)(vd & 63) * 8 + (p & 7)] = (f16)acc[mt][nt][r];
                    }
        } else {
            const float sc = (which == 0) ? 0.18033688011112042f : 1.0f;
            f16* Ts = (f16*)smem;  // 64 x stride-136
            for (int ph = 0; ph < 2; ph++) {
                __syncthreads();
                if (wn == ph) {
                    for (int mt = 0; mt < 4; mt++)
                        for (int nt = 0; nt < 4; nt++)
                            for (int r = 0; r < 4; r++)
                                Ts[(nt * 16 + l16) * 136 + wm * 64 + mt * 16 +
                                   g * 4 + r] = (f16)(acc[mt][nt][r] * sc);
                }
                __syncthreads();
                const int row = tid >> 2;
                const int p = nBase + ph * 64 + row;
                for (int cc = 0; cc < 4; cc++) {
                    const int c8 = (tid & 3) * 4 + cc;
                    f16x8 v = *(const f16x8*)&Ts[row * 136 + c8 * 8];
                    const int o = mBase + c8 * 8;
                    const int head = (o >> 6) & 7;
                    const int d = o & 63;
                    if (which == 0)
                        *(f16x8*)&qb[(size_t)head * 262144 + (size_t)p * 64 + d] = v;
                    else
                        *(f16x8*)&kb[(size_t)head * 262144 +
                                     (size_t)(d >> 3) * 32768 + (size_t)p * 8] = v;
                }
            }
        }
    }
    gridbar(bar + 1);

    // ===== stage 2: flash attention (all 512 blocks), R8 verbatim ===========
    {
        f16* Ks = (f16*)smem;                  // 2 x 8KB
        f16* Vs = (f16*)(smem + 16384);        // 2 x 8KB
        const int l31 = lane & 31, hi = lane >> 5;
        const int h = bid & 7, rest = bid >> 3, it = rest >> 1, s = rest & 1;
        const f16* Qw = qb + (size_t)h * 262144 + (size_t)(it * 128 + w * 32) * 64;
        const f16* Kh = kb + (size_t)h * 262144;
        const f16* Vh = vb + (size_t)h * 262144;

        const int q = (lane >> 2) & 3;
        const int rg = lane + ((q == 1) ? 4 : (q == 2) ? -4 : 0);

        const int c0 = w * 2, c1 = w * 2 + 1;
        const f16* kS0 = Kh + (size_t)c0 * 32768 + (size_t)(s * 2048 + rg) * 8;
        const f16* kS1 = Kh + (size_t)c1 * 32768 + (size_t)(s * 2048 + rg) * 8;
        const f16* vS0 = Vh + (size_t)(s * 256 + c0) * 512 + (size_t)lane * 8;
        const f16* vS1 = Vh + (size_t)(s * 256 + c1) * 512 + (size_t)lane * 8;

#define STAGE(T, BUF)                                                       \
    {                                                                       \
        load_lds16(kS0 + (T) * 512, &Ks[(BUF) * 4096 + c0 * 512]);          \
        load_lds16(kS1 + (T) * 512, &Ks[(BUF) * 4096 + c1 * 512]);          \
        load_lds16(vS0 + (T) * 4096, &Vs[(BUF) * 4096 + c0 * 512]);         \
        load_lds16(vS1 + (T) * 4096, &Vs[(BUF) * 4096 + c1 * 512]);         \
    }

        STAGE(0, 0);

        f16x8 qf[4];
#pragma unroll
        for (int ks = 0; ks < 4; ks++)
            qf[ks] = *(const f16x8*)(Qw + l31 * 64 + ks * 16 + hi * 8);

        f32x16 oacc[2] = {};
        float2 lsum = {0.f, 0.f};
        const h16x2 one2 = {(__fp16)1.0f, (__fp16)1.0f};

        __syncthreads();

#pragma unroll 4
        for (int jt = 0; jt < 32; jt++) {
            const int cur = jt & 1;
            if (jt < 31) STAGE(jt + 1, cur ^ 1);
            const int co = cur * 4096;
            f16x8 kfa[4];
#pragma unroll
            for (int ks = 0; ks < 4; ks++)
                kfa[ks] = *(const f16x8*)&Ks[co + (ks * 2 + hi) * 512 + l31 * 8];
            f32x16 sv0 = {};
#pragma unroll
            for (int ks = 0; ks < 4; ks++) sv0 = MFMA3216(kfa[ks], qf[ks], sv0);
            f16x8 kfb[4];
#pragma unroll
            for (int ks = 0; ks < 4; ks++)
                kfb[ks] = *(const f16x8*)&Ks[co + (ks * 2 + hi) * 512 +
                                             (32 + l31) * 8];
            f32x16 sv1 = {};
            sv1 = MFMA3216(kfb[0], qf[0], sv1);
            f16x8 pa00 = soft_half(sv0, 0, lsum, one2);
            sv1 = MFMA3216(kfb[1], qf[1], sv1);
            f16x8 pa01 = soft_half(sv0, 8, lsum, one2);
            sv1 = MFMA3216(kfb[2], qf[2], sv1);
            f16x8 bv0[4];
#pragma unroll
            for (int k2 = 0; k2 < 2; k2++)
#pragma unroll
                for (int dt = 0; dt < 2; dt++)
                    bv0[k2 * 2 + dt] = *(const f16x8*)&Vs[co + (k2 * 2 + hi) * 512 +
                                                          (dt * 32 + l31) * 8];
            sv1 = MFMA3216(kfb[3], qf[3], sv1);
            oacc[0] = MFMA3216(pa00, bv0[0], oacc[0]);
            oacc[1] = MFMA3216(pa00, bv0[1], oacc[1]);
            oacc[0] = MFMA3216(pa01, bv0[2], oacc[0]);
            oacc[1] = MFMA3216(pa01, bv0[3], oacc[1]);
            f16x8 bv1[4];
#pragma unroll
            for (int k2 = 0; k2 < 2; k2++)
#pragma unroll
                for (int dt = 0; dt < 2; dt++)
                    bv1[k2 * 2 + dt] = *(const f16x8*)&Vs[co + (4 + k2 * 2 + hi) * 512 +
                                                          (dt * 32 + l31) * 8];
            __syncthreads();
            f16x8 pa10 = soft_half(sv1, 0, lsum, one2);
            oacc[0] = MFMA3216(pa10, bv1[0], oacc[0]);
            oacc[1] = MFMA3216(pa10, bv1[1], oacc[1]);
            f16x8 pa11 = soft_half(sv1, 8, lsum, one2);
            oacc[0] = MFMA3216(pa11, bv1[2], oacc[0]);
            oacc[1] = MFMA3216(pa11, bv1[3], oacc[1]);
        }
#undef STAGE

        float ls = lsum.x + lsum.y;
        ls += __shfl_xor(ls, 32);
        if (lane < 32)
            Lp[(size_t)s * 32768 + (size_t)(it * 128 + w * 32 + lane) * 8 + h] = ls;
        f16* Oh = Op + (size_t)s * 2097152 + (size_t)(it * 128 + w * 32) * 512 +
                  h * 64;
#pragma unroll
        for (int dt = 0; dt < 2; dt++)
#pragma unroll
            for (int r = 0; r < 16; r++) {
                const int i = (r & 3) + 8 * (r >> 2) + 4 * hi;
                Oh[(size_t)i * 512 + dt * 32 + l31] = (f16)oacc[dt][r];
            }
    }
    gridbar(bar + 2);

    // ===== stage 3: out GEMM (all 512 blocks), R12 dbuf verbatim ============
    {
        f16* As = (f16*)smem;                  // 2 x 8KB
        f16* Bs = (f16*)(smem + 16384);        // 2 x 4KB
        float* invL = (float*)(smem + 24576);  // 32 p x 8 h
        const int mBase = (bid >> 7) * 64, nBase = (bid & 127) * 32;

        {
            const int idx = tid;
            const int p = nBase + (idx >> 3), hh = idx & 7;
            float sum = 0.f;
            for (int s4 = 0; s4 < 2; s4++)
                sum += Lp[(size_t)s4 * 32768 + p * 8 + hh];
            invL[idx] = 1.0f / sum;
        }
        __syncthreads();

        f32x4 acc[2] = {};

#define STAGEO(KT, BUF)                                                     \
    {                                                                       \
        for (int c = 0; c < 2; c++) {                                       \
            const int L = c * 256 + tid;                                    \
            const int row = L >> 3;                                         \
            load_lds16(woh + (size_t)(mBase + row) * 512 + (KT) * 64 +      \
                           (((L & 7) ^ (row & 7)) * 8),                     \
                       &As[(BUF) * 4096 + (c * 256 + (tid & ~63)) * 8]);    \
        }                                                                   \
        {                                                                   \
            const int L = tid;                                              \
            const int row = L >> 3, ch = L & 7;                             \
            const int gc = ch ^ (row & 7);                                  \
            const f16* op0 = Op + (size_t)(nBase + row) * 512 + (KT) * 64 + \
                             gc * 8;                                        \
            f16x8 b0 = *(const f16x8*)(op0);                                \
            f16x8 b1 = *(const f16x8*)(op0 + 2097152);                      \
            const f16 iv = (f16)invL[row * 8 + (KT)];                       \
            f16x8 bsum = (b0 + b1) * iv;                                    \
            *(f16x8*)&Bs[(BUF) * 2048 + L * 8] = bsum;                      \
        }                                                                   \
    }

        STAGEO(0, 0);
        __syncthreads();

        for (int kt = 0; kt < 8; kt++) {
            const int cur = kt & 1;
            if (kt < 7) STAGEO(kt + 1, cur ^ 1);
            const int ab = cur * 4096, bb = cur * 2048;
            for (int ks = 0; ks < 2; ks++) {
                const int chv = ((ks * 4 + g) ^ swz) * 8;
                f16x8 af[2], bf;
                for (int t = 0; t < 2; t++)
                    af[t] = *(const f16x8*)&As[ab + (wm * 32 + t * 16 + l16) * 64 + chv];
                bf = *(const f16x8*)&Bs[bb + (wn * 16 + l16) * 64 + chv];
                for (int mt = 0; mt < 2; mt++)
                    acc[mt] = MFMA32(af[mt], bf, acc[mt]);
            }
            __syncthreads();
        }
#undef STAGEO

        for (int mt = 0; mt < 2; mt++)
            for (int r = 0; r < 4; r++) {
                const int o = mBase + wm * 32 + mt * 16 + g * 4 + r;
                const float bb2 = bias[o];
                const int p = nBase + wn * 16 + l16;
                out[(size_t)o * 4096 + p] = acc[mt][r] + bb2;
            }
    }
}

// ---------------------------------------------------------------------------
extern "C" void kernel_launch(void* const* d_in, const int* in_sizes, int n_in,
                              void* d_out, int out_size, void* d_ws, size_t ws_size,
                              hipStream_t stream) {
    const float* x    = (const float*)d_in[0];  // (1,256,64,64)
    const float* wqkv = (const float*)d_in[1];  // (1536,256)
    const float* wout = (const float*)d_in[2];  // (256,512)
    const float* bout = (const float*)d_in[3];  // (256,)
    float* out = (float*)d_out;                 // (1,256,64,64)

    char* ws = (char*)d_ws;
    float* Lp = (float*)(ws);                    // [0,256K)
    f16* qb = (f16*)(ws + (2u << 20));           // [2M,6M)  [head][p][d]
    f16* kb = (f16*)(ws + (6u << 20));           // [6M,10M) [head][dchunk][j][8]
    f16* vb = (f16*)(ws + (10u << 20));          // [10M,14M) [head][jchunk][d][8]
    f16* Op = (f16*)(ws + (14u << 20));          // [14M,22M) 2 split halves
    f16* wqh = (f16*)(ws + (22u << 20));         // wqkv f16
    f16* woh = (f16*)(ws + (23u << 20));         // wout f16
    f16* xh = (f16*)(ws + (30u << 20));          // transposed x
    unsigned* bar = (unsigned*)(ws + (33u << 20));  // 3 grid-barrier counters

    hipMemsetAsync(bar, 0, 16, stream);
    fused<<<dim3(512), 256, 0, stream>>>(x, wqkv, wout, bout, out, xh, wqh, woh,
                                         qb, kb, vb, Op, Lp, bar);
}

// Round 15
// 125.115 us; speedup vs baseline: 2.7688x; 2.7688x over previous
//
#include <hip/hip_runtime.h>
#include <math.h>

typedef _Float16 f16;
typedef __attribute__((ext_vector_type(4))) _Float16 f16x4;
typedef __attribute__((ext_vector_type(8))) _Float16 f16x8;
typedef __attribute__((ext_vector_type(2))) __fp16 h16x2;
typedef __attribute__((ext_vector_type(4))) __fp16 h16x4;
typedef __attribute__((ext_vector_type(4))) float f32x4;
typedef __attribute__((ext_vector_type(16))) float f32x16;

__device__ __forceinline__ void load_lds16(const void* g, void* l) {
    __builtin_amdgcn_global_load_lds((const __attribute__((address_space(1))) void*)g,
                                     (__attribute__((address_space(3))) void*)l, 16, 0, 0);
}

__device__ __forceinline__ float fast_exp2(float x) {
#if __has_builtin(__builtin_amdgcn_exp2f)
    return __builtin_amdgcn_exp2f(x);
#else
    return __exp2f(x);
#endif
}

#define MFMA32(a, b, c) __builtin_amdgcn_mfma_f32_16x16x32_f16(a, b, c, 0, 0, 0)
#define MFMA3216(a, b, c) __builtin_amdgcn_mfma_f32_32x32x16_f16(a, b, c, 0, 0, 0)

// ---------------------------------------------------------------------------
// Kernel 1 (R12-passing verbatim): x[c][p] fp32 -> xh[p][c] fp16 (y=0..3),
// y=4 converts wqkv/wout fp32 -> f16.
// ---------------------------------------------------------------------------
__global__ __launch_bounds__(256) void kxpose(const float* __restrict__ x,
                                              f16* __restrict__ xh,
                                              const float* __restrict__ wqkv,
                                              f16* __restrict__ wqh,
                                              const float* __restrict__ wout,
                                              f16* __restrict__ woh) {
    if (blockIdx.y == 4) {
        const int t = blockIdx.x * 256 + threadIdx.x;   // 16384 threads
        for (int i = t; i < 98304; i += 16384) {        // wqkv: 393216 f32
            float4 u = ((const float4*)wqkv)[i];
            f16x4 hv; hv[0] = (f16)u.x; hv[1] = (f16)u.y;
            hv[2] = (f16)u.z; hv[3] = (f16)u.w;
            ((f16x4*)wqh)[i] = hv;
        }
        for (int i = t; i < 32768; i += 16384) {        // wout: 131072 f32
            float4 u = ((const float4*)wout)[i];
            f16x4 hv; hv[0] = (f16)u.x; hv[1] = (f16)u.y;
            hv[2] = (f16)u.z; hv[3] = (f16)u.w;
            ((f16x4*)woh)[i] = hv;
        }
        return;
    }
    __shared__ f16 t[64][65];
    const int p0 = blockIdx.x * 64;
    const int c0 = blockIdx.y * 64;
    const int lp = threadIdx.x & 63;
    const int lq = threadIdx.x >> 6;
    for (int i = 0; i < 64; i += 4)
        t[i + lq][lp] = (f16)x[(size_t)(c0 + i + lq) * 4096 + p0 + lp];
    __syncthreads();
    for (int i = 0; i < 64; i += 4)
        xh[(size_t)(p0 + i + lq) * 256 + c0 + lp] = t[lp][i + lq];
}

// ---------------------------------------------------------------------------
// Kernel 2 (R12-passing verbatim): QKV GEMM, BM=BN=128 (grid 32x12). BOTH A
// (f16 weights) and B staged via global_load_lds, single-buffered.
// Epilogues: q -> [head][p][d]; k -> [head][dchunk][j][8]; v ->
// [head][jchunk][d][8]. q pre-scaled 0.125*log2e.
// ---------------------------------------------------------------------------
__global__ __launch_bounds__(256) void gemm_qkv(
        const f16* __restrict__ A, const f16* __restrict__ B,
        f16* __restrict__ qb, f16* __restrict__ kb, f16* __restrict__ vb) {
    __shared__ __align__(16) char smem[32768];
    f16* As = (f16*)smem;
    f16* Bs = (f16*)(smem + 16384);
    const int K = 256, tid = threadIdx.x;
    const int w = tid >> 6, lane = tid & 63, l16 = lane & 15, g = lane >> 4;
    const int wm = w >> 1, wn = w & 1;
    const int mBase = blockIdx.y * 128, nBase = blockIdx.x * 128;
    const int swz = lane & 7;

    f32x4 acc[4][4] = {};

    for (int k0 = 0; k0 < K; k0 += 64) {
        for (int c = 0; c < 4; c++) {
            const int L = c * 256 + w * 64 + lane;
            const int row = L >> 3;
            load_lds16(A + (size_t)(mBase + row) * K + k0 + (((L & 7) ^ (row & 7)) * 8),
                       &As[(c * 256 + w * 64) * 8]);
        }
        for (int c = 0; c < 4; c++) {
            const int L = c * 256 + w * 64 + lane;
            const int row = L >> 3;
            load_lds16(B + (size_t)(nBase + row) * K + k0 + (((L & 7) ^ (row & 7)) * 8),
                       &Bs[(c * 256 + w * 64) * 8]);
        }
        __syncthreads();
        for (int ks = 0; ks < 2; ks++) {
            const int ch = ((ks * 4 + g) ^ swz) * 8;
            f16x8 af[4], bf[4];
            for (int t = 0; t < 4; t++)
                af[t] = *(const f16x8*)&As[(wm * 64 + t * 16 + l16) * 64 + ch];
            for (int t = 0; t < 4; t++)
                bf[t] = *(const f16x8*)&Bs[(wn * 64 + t * 16 + l16) * 64 + ch];
            for (int mt = 0; mt < 4; mt++)
                for (int nt = 0; nt < 4; nt++)
                    acc[mt][nt] = MFMA32(af[mt], bf[nt], acc[mt][nt]);
        }
        __syncthreads();
    }

    const int which = mBase >> 9;  // 0=q, 1=k, 2=v (block-uniform)
    if (which == 2) {
        // V: direct from C-layout into [head][jchunk][d][8]
        for (int mt = 0; mt < 4; mt++)
            for (int nt = 0; nt < 4; nt++)
                for (int r = 0; r < 4; r++) {
                    const int o = mBase + wm * 64 + mt * 16 + g * 4 + r;
                    const int p = nBase + wn * 64 + nt * 16 + l16;
                    const int vd = o - 1024;
                    vb[(size_t)(vd >> 6) * 262144 + (size_t)(p >> 3) * 512 +
                       (size_t)(vd & 63) * 8 + (p & 7)] = (f16)acc[mt][nt][r];
                }
    } else {
        const float sc = (which == 0) ? 0.18033688011112042f : 1.0f;  // 0.125*log2e
        f16* Ts = (f16*)smem;  // 64 x stride-136 = 17408 B
        for (int ph = 0; ph < 2; ph++) {
            __syncthreads();
            if (wn == ph) {
                for (int mt = 0; mt < 4; mt++)
                    for (int nt = 0; nt < 4; nt++)
                        for (int r = 0; r < 4; r++)
                            Ts[(nt * 16 + l16) * 136 + wm * 64 + mt * 16 + g * 4 + r] =
                                (f16)(acc[mt][nt][r] * sc);
            }
            __syncthreads();
            const int row = tid >> 2;                 // p within half
            const int p = nBase + ph * 64 + row;
            for (int cc = 0; cc < 4; cc++) {
                const int c8 = (tid & 3) * 4 + cc;    // 8-f16 chunk of o
                f16x8 v = *(const f16x8*)&Ts[row * 136 + c8 * 8];
                const int o = mBase + c8 * 8;
                const int head = (o >> 6) & 7;
                const int d = o & 63;
                if (which == 0)
                    *(f16x8*)&qb[(size_t)head * 262144 + (size_t)p * 64 + d] = v;
                else
                    *(f16x8*)&kb[(size_t)head * 262144 + (size_t)(d >> 3) * 32768 +
                                 (size_t)p * 8] = v;
            }
        }
    }
}

// ---------------------------------------------------------------------------
// Helper: softmax HALF a 32-wide S tile (8 f32) -> 1 PV A-fragment.
// ---------------------------------------------------------------------------
__device__ __forceinline__ f16x8 soft_half(const f32x16 sv, const int base,
                                           float2& ls, const h16x2 one2) {
    h16x2 c0 = __builtin_amdgcn_cvt_pkrtz(fast_exp2(sv[base + 0]),
                                          fast_exp2(sv[base + 1]));
    h16x2 c1 = __builtin_amdgcn_cvt_pkrtz(fast_exp2(sv[base + 2]),
                                          fast_exp2(sv[base + 3]));
    h16x2 c2 = __builtin_amdgcn_cvt_pkrtz(fast_exp2(sv[base + 4]),
                                          fast_exp2(sv[base + 5]));
    h16x2 c3 = __builtin_amdgcn_cvt_pkrtz(fast_exp2(sv[base + 6]),
                                          fast_exp2(sv[base + 7]));
    ls.x = __builtin_amdgcn_fdot2(c0, one2, ls.x, false);
    ls.y = __builtin_amdgcn_fdot2(c1, one2, ls.y, false);
    ls.x = __builtin_amdgcn_fdot2(c2, one2, ls.x, false);
    ls.y = __builtin_amdgcn_fdot2(c3, one2, ls.y, false);
    h16x4 plo = __builtin_shufflevector(c0, c1, 0, 1, 2, 3);
    h16x4 phi = __builtin_shufflevector(c2, c3, 0, 1, 2, 3);
    return __builtin_bit_cast(
        f16x8, __builtin_shufflevector(plo, phi, 0, 1, 2, 3, 4, 5, 6, 7));
}

// ---------------------------------------------------------------------------
// Kernel 3 (R8-passing verbatim, session-best attn): flash attention. NO
// setprio, hand-interleaved trans/MFMA. 32 i-rows/wave, 128/block; grid 512
// = 8h x 32it x 2s (2 blocks/CU). LDS 32KB dbuf chunk-major (conflict-free
// frag reads, K quartet permutation on staging source so QK C-regs feed PV
// A directly).
// ---------------------------------------------------------------------------
__global__ __launch_bounds__(256, 2) void attn_fwd(
        const f16* __restrict__ qb, const f16* __restrict__ kb,
        const f16* __restrict__ vb, f16* __restrict__ Op, float* __restrict__ Lp) {
    __shared__ __align__(16) char smem[32768];
    f16* Ks = (f16*)smem;                  // 2 x 8KB: [c 0..7][row 0..63][8]
    f16* Vs = (f16*)(smem + 16384);        // 2 x 8KB: [jc 0..7][d 0..63][8]
    const int tid = threadIdx.x;
    const int w = tid >> 6, lane = tid & 63, l31 = lane & 31, hi = lane >> 5;
    const int bx = blockIdx.x;
    const int h = bx & 7, rest = bx >> 3, it = rest >> 1, s = rest & 1;
    const f16* Qw = qb + (size_t)h * 262144 + (size_t)(it * 128 + w * 32) * 64;
    const f16* Kh = kb + (size_t)h * 262144;   // [dchunk 8][j 4096][8]
    const f16* Vh = vb + (size_t)h * 262144;   // [jchunk 512][d 64][8]

    // K row permutation within 16-groups: swap quartets 1<->2
    const int q = (lane >> 2) & 3;
    const int rg = lane + ((q == 1) ? 4 : (q == 2) ? -4 : 0);

    const int c0 = w * 2, c1 = w * 2 + 1;
    const f16* kS0 = Kh + (size_t)c0 * 32768 + (size_t)(s * 2048 + rg) * 8;
    const f16* kS1 = Kh + (size_t)c1 * 32768 + (size_t)(s * 2048 + rg) * 8;
    const f16* vS0 = Vh + (size_t)(s * 256 + c0) * 512 + (size_t)lane * 8;
    const f16* vS1 = Vh + (size_t)(s * 256 + c1) * 512 + (size_t)lane * 8;

#define STAGE(T, BUF)                                                       \
    {                                                                       \
        load_lds16(kS0 + (T) * 512, &Ks[(BUF) * 4096 + c0 * 512]);          \
        load_lds16(kS1 + (T) * 512, &Ks[(BUF) * 4096 + c1 * 512]);          \
        load_lds16(vS0 + (T) * 4096, &Vs[(BUF) * 4096 + c0 * 512]);         \
        load_lds16(vS1 + (T) * 4096, &Vs[(BUF) * 4096 + c1 * 512]);         \
    }

    STAGE(0, 0);

    // Q B-fragments: col = i = l31, k = ks*16 + hi*8 + e
    f16x8 qf[4];
#pragma unroll
    for (int ks = 0; ks < 4; ks++)
        qf[ks] = *(const f16x8*)(Qw + l31 * 64 + ks * 16 + hi * 8);

    f32x16 oacc[2] = {};
    float2 lsum = {0.f, 0.f};
    const h16x2 one2 = {(__fp16)1.0f, (__fp16)1.0f};

    __syncthreads();

#pragma unroll 4
    for (int jt = 0; jt < 32; jt++) {
        const int cur = jt & 1;
        if (jt < 31) STAGE(jt + 1, cur ^ 1);
        const int co = cur * 4096;
        // --- QK unit 0 (rows 0..31) ---
        f16x8 kfa[4];
#pragma unroll
        for (int ks = 0; ks < 4; ks++)
            kfa[ks] = *(const f16x8*)&Ks[co + (ks * 2 + hi) * 512 + l31 * 8];
        f32x16 sv0 = {};
#pragma unroll
        for (int ks = 0; ks < 4; ks++) sv0 = MFMA3216(kfa[ks], qf[ks], sv0);
        // --- QK unit 1 interleaved with softmax of unit 0 ---
        f16x8 kfb[4];
#pragma unroll
        for (int ks = 0; ks < 4; ks++)
            kfb[ks] = *(const f16x8*)&Ks[co + (ks * 2 + hi) * 512 + (32 + l31) * 8];
        f32x16 sv1 = {};
        sv1 = MFMA3216(kfb[0], qf[0], sv1);
        f16x8 pa00 = soft_half(sv0, 0, lsum, one2);
        sv1 = MFMA3216(kfb[1], qf[1], sv1);
        f16x8 pa01 = soft_half(sv0, 8, lsum, one2);
        sv1 = MFMA3216(kfb[2], qf[2], sv1);
        f16x8 bv0[4];
#pragma unroll
        for (int k2 = 0; k2 < 2; k2++)
#pragma unroll
            for (int dt = 0; dt < 2; dt++)
                bv0[k2 * 2 + dt] = *(const f16x8*)&Vs[co + (k2 * 2 + hi) * 512 +
                                                      (dt * 32 + l31) * 8];
        sv1 = MFMA3216(kfb[3], qf[3], sv1);
        // --- PV unit 0 ---
        oacc[0] = MFMA3216(pa00, bv0[0], oacc[0]);
        oacc[1] = MFMA3216(pa00, bv0[1], oacc[1]);
        oacc[0] = MFMA3216(pa01, bv0[2], oacc[0]);
        oacc[1] = MFMA3216(pa01, bv0[3], oacc[1]);
        // --- last cur-buffer reads, then barrier ---
        f16x8 bv1[4];
#pragma unroll
        for (int k2 = 0; k2 < 2; k2++)
#pragma unroll
            for (int dt = 0; dt < 2; dt++)
                bv1[k2 * 2 + dt] = *(const f16x8*)&Vs[co + (4 + k2 * 2 + hi) * 512 +
                                                      (dt * 32 + l31) * 8];
        __syncthreads();
        // --- softmax unit 1 interleaved with PV unit 1 (register-only) ---
        f16x8 pa10 = soft_half(sv1, 0, lsum, one2);
        oacc[0] = MFMA3216(pa10, bv1[0], oacc[0]);
        oacc[1] = MFMA3216(pa10, bv1[1], oacc[1]);
        f16x8 pa11 = soft_half(sv1, 8, lsum, one2);
        oacc[0] = MFMA3216(pa11, bv1[2], oacc[0]);
        oacc[1] = MFMA3216(pa11, bv1[3], oacc[1]);
    }
#undef STAGE

    float ls = lsum.x + lsum.y;
    ls += __shfl_xor(ls, 32);
    if (lane < 32)
        Lp[(size_t)s * 32768 + (size_t)(it * 128 + w * 32 + lane) * 8 + h] = ls;
    f16* Oh = Op + (size_t)s * 2097152 + (size_t)(it * 128 + w * 32) * 512 + h * 64;
#pragma unroll
    for (int dt = 0; dt < 2; dt++)
#pragma unroll
        for (int r = 0; r < 16; r++) {
            const int i = (r & 3) + 8 * (r >> 2) + 4 * hi;
            Oh[(size_t)i * 512 + dt * 32 + l31] = (f16)oacc[dt][r];
        }
}

// ---------------------------------------------------------------------------
// Kernel 4 (R12-passing verbatim): out GEMM with fused combine (2 partials).
// BM=64 BN=32, grid (128,4) = 512 blocks (2/CU), DOUBLE-BUFFERED.
// ---------------------------------------------------------------------------
__global__ __launch_bounds__(256) void gemm_out(
        const f16* __restrict__ A, const f16* __restrict__ Op,
        const float* __restrict__ Lp, const float* __restrict__ bias,
        float* __restrict__ C) {
    __shared__ __align__(16) char smem[25600];
    f16* As = (f16*)smem;                  // 2 x 8KB
    f16* Bs = (f16*)(smem + 16384);        // 2 x 4KB
    float* invL = (float*)(smem + 24576);  // 32 p x 8 h
    const int tid = threadIdx.x;
    const int w = tid >> 6, lane = tid & 63, l16 = lane & 15, g = lane >> 4;
    const int wm = w >> 1, wn = w & 1;
    const int mBase = blockIdx.y * 64, nBase = blockIdx.x * 32;
    const int swz = lane & 7;

    {
        const int idx = tid;                   // p_loc*8 + h (256 entries)
        const int p = nBase + (idx >> 3), hh = idx & 7;
        float sum = 0.f;
        for (int s4 = 0; s4 < 2; s4++) sum += Lp[(size_t)s4 * 32768 + p * 8 + hh];
        invL[idx] = 1.0f / sum;
    }
    __syncthreads();

    f32x4 acc[2] = {};

#define STAGEO(KT, BUF)                                                     \
    {                                                                       \
        for (int c = 0; c < 2; c++) {          /* A: 64x64 f16 */           \
            const int L = c * 256 + tid;                                    \
            const int row = L >> 3;                                         \
            load_lds16(A + (size_t)(mBase + row) * 512 + (KT) * 64 +        \
                           (((L & 7) ^ (row & 7)) * 8),                     \
                       &As[(BUF) * 4096 + (c * 256 + (tid & ~63)) * 8]);    \
        }                                                                   \
        {                                      /* B: 32x64 combine */       \
            const int L = tid;                                              \
            const int row = L >> 3, ch = L & 7;                             \
            const int gc = ch ^ (row & 7);                                  \
            const f16* op0 = Op + (size_t)(nBase + row) * 512 + (KT) * 64 + \
                             gc * 8;                                        \
            f16x8 b0 = *(const f16x8*)(op0);                                \
            f16x8 b1 = *(const f16x8*)(op0 + 2097152);                      \
            const f16 iv = (f16)invL[row * 8 + (KT)];                       \
            f16x8 bsum = (b0 + b1) * iv;                                    \
            *(f16x8*)&Bs[(BUF) * 2048 + L * 8] = bsum;                      \
        }                                                                   \
    }

    STAGEO(0, 0);
    __syncthreads();

    for (int kt = 0; kt < 8; kt++) {
        const int cur = kt & 1;
        if (kt < 7) STAGEO(kt + 1, cur ^ 1);
        const int ab = cur * 4096, bb = cur * 2048;
        for (int ks = 0; ks < 2; ks++) {
            const int chv = ((ks * 4 + g) ^ swz) * 8;
            f16x8 af[2], bf;
            for (int t = 0; t < 2; t++)
                af[t] = *(const f16x8*)&As[ab + (wm * 32 + t * 16 + l16) * 64 + chv];
            bf = *(const f16x8*)&Bs[bb + (wn * 16 + l16) * 64 + chv];
            for (int mt = 0; mt < 2; mt++)
                acc[mt] = MFMA32(af[mt], bf, acc[mt]);
        }
        __syncthreads();
    }
#undef STAGEO

    for (int mt = 0; mt < 2; mt++)
        for (int r = 0; r < 4; r++) {
            const int o = mBase + wm * 32 + mt * 16 + g * 4 + r;
            const float bb2 = bias[o];
            const int p = nBase + wn * 16 + l16;
            C[(size_t)o * 4096 + p] = acc[mt][r] + bb2;
        }
}

// ---------------------------------------------------------------------------
extern "C" void kernel_launch(void* const* d_in, const int* in_sizes, int n_in,
                              void* d_out, int out_size, void* d_ws, size_t ws_size,
                              hipStream_t stream) {
    const float* x    = (const float*)d_in[0];  // (1,256,64,64)
    const float* wqkv = (const float*)d_in[1];  // (1536,256)
    const float* wout = (const float*)d_in[2];  // (256,512)
    const float* bout = (const float*)d_in[3];  // (256,)
    float* out = (float*)d_out;                 // (1,256,64,64)

    char* ws = (char*)d_ws;
    float* Lp = (float*)(ws);                    // [0,256K) written by attn
    f16* qb = (f16*)(ws + (2u << 20));           // [2M,6M)  [head][p][d]
    f16* kb = (f16*)(ws + (6u << 20));           // [6M,10M) [head][dchunk][j][8]
    f16* vb = (f16*)(ws + (10u << 20));          // [10M,14M) [head][jchunk][d][8]
    f16* Op = (f16*)(ws + (14u << 20));          // [14M,22M) 2 split halves
    f16* wqh = (f16*)(ws + (22u << 20));         // [22M,~22.75M) wqkv f16
    f16* woh = (f16*)(ws + (23u << 20));         // [23M,~23.25M) wout f16
    f16* xh = (f16*)(ws + (30u << 20));          // [30M,32M) transposed x

    kxpose<<<dim3(64, 5), 256, 0, stream>>>(x, xh, wqkv, wqh, wout, woh);
    gemm_qkv<<<dim3(32, 12), 256, 0, stream>>>(wqh, xh, qb, kb, vb);
    attn_fwd<<<dim3(512), 256, 0, stream>>>(qb, kb, vb, Op, Lp);
    gemm_out<<<dim3(128, 4), 256, 0, stream>>>(woh, Op, Lp, bout, out);
}